// Round 3
// baseline (408.685 us; speedup 1.0000x reference)
//
#include <hip/hip_runtime.h>

typedef _Float16 f16;
typedef _Float16 f16x4 __attribute__((ext_vector_type(4)));
typedef _Float16 f16x8 __attribute__((ext_vector_type(8)));
typedef float f32x4 __attribute__((ext_vector_type(4)));

// workspace byte offsets
#define WS_BIAS    0          // 8*64*64 f16 = 65536 (permuted layout)
#define WS_TBL     65536      // 169*8 f32 = 5408
#define WS_QKVWT   73728      // 768*256 f16 = 393216
#define WS_PROJWT  466944     // 256*256 f16 = 131072

// ---------------- CPB MLP: one block per table entry ----------------
__global__ __launch_bounds__(512) void cpb_mlp_kernel(
    const float* __restrict__ w1, const float* __restrict__ b1,
    const float* __restrict__ w2, float* __restrict__ tbl)
{
    const int bid = blockIdx.x;            // 0..168
    const int i = bid / 13, j = bid % 13;
    float t0 = 8.0f * (float)(i - 6) / 6.0f;
    float t1 = 8.0f * (float)(j - 6) / 6.0f;
    const float invlog8 = 0.4808983469629878f;
    t0 = copysignf(log1pf(fabsf(t0)) * invlog8, t0);
    t1 = copysignf(log1pf(fabsf(t1)) * invlog8, t1);

    const int t = threadIdx.x;             // hidden unit
    float pre = t0 * w1[t] + t1 * w1[512 + t] + b1[t];
    float g = 0.5f * pre * (1.0f + erff(pre * 0.70710678118654752f));
    float a[8];
#pragma unroll
    for (int h = 0; h < 8; ++h) a[h] = g * w2[t * 8 + h];
#pragma unroll
    for (int off = 1; off < 64; off <<= 1)
#pragma unroll
        for (int h = 0; h < 8; ++h) a[h] += __shfl_xor(a[h], off, 64);

    __shared__ float wred[8][8];
    const int w = t >> 6, lane = t & 63;
    if (lane == 0)
#pragma unroll
        for (int h = 0; h < 8; ++h) wred[w][h] = a[h];
    __syncthreads();
    if (t < 8) {
        float s = 0.f;
#pragma unroll
        for (int ww = 0; ww < 8; ++ww) s += wred[ww][t];
        tbl[bid * 8 + t] = s;
    }
}

// ---- scatter bias -> f16 [8][64][64], col permuted so (row,l15) -> 4 contiguous
__global__ __launch_bounds__(256) void cpb_bias_kernel(
    const float* __restrict__ tbl, f16* __restrict__ bias_f16)
{
    int idx = blockIdx.x * 256 + threadIdx.x;   // h*4096 + r*64 + c
    int h = idx >> 12, r = (idx >> 6) & 63, c = idx & 63;
    float v = 0.f;
    if (r < 49 && c < 49) {
        int dh = r / 7 - c / 7 + 6;
        int dw = r % 7 - c % 7 + 6;
        float bv = tbl[(dh * 13 + dw) * 8 + h];
        v = 16.0f / (1.0f + __expf(-bv));
    }
    int cc = (c & 15) * 4 + (c >> 4);           // [l15][nt] interleave
    bias_f16[(h << 12) + (r << 6) + cc] = (f16)v;
}

// ---------------- weight transpose via LDS tiles ----------------
__global__ __launch_bounds__(256) void wconv_kernel(
    const float* __restrict__ qkv_w, const float* __restrict__ proj_w,
    f16* __restrict__ qkv_wT, f16* __restrict__ proj_wT)
{
    __shared__ float ts[64][65];
    int b = blockIdx.x;
    const float* src; f16* dst; int W, kb, nb;
    if (b < 48) { src = qkv_w;  dst = qkv_wT;  W = 768; kb = b / 12; nb = b % 12; }
    else { b -= 48; src = proj_w; dst = proj_wT; W = 256; kb = b / 4;  nb = b % 4; }
    const int t = threadIdx.x;
#pragma unroll
    for (int it = 0; it < 4; ++it) {
        int k = it * 16 + (t >> 4);
        int n4 = (t & 15) * 4;
        float4 v = *(const float4*)(src + (size_t)(kb * 64 + k) * W + nb * 64 + n4);
        ts[k][n4] = v.x; ts[k][n4 + 1] = v.y; ts[k][n4 + 2] = v.z; ts[k][n4 + 3] = v.w;
    }
    __syncthreads();
#pragma unroll
    for (int it = 0; it < 4; ++it) {
        int n = it * 16 + (t >> 4);
        int k4 = (t & 15) * 4;
        f16x4 hv;
        hv[0] = (f16)ts[k4][n]; hv[1] = (f16)ts[k4 + 1][n];
        hv[2] = (f16)ts[k4 + 2][n]; hv[3] = (f16)ts[k4 + 3][n];
        *(f16x4*)(dst + (size_t)(nb * 64 + n) * 256 + kb * 64 + k4) = hv;
    }
}

// ---------------- fully fused: qkv + attention + proj ----------------
// block = one window; 8 waves, wave = one head. 135 KB LDS -> 1 block/CU.
__global__ __launch_bounds__(512, 2) void fused_kernel(
    const float* __restrict__ x, const float* __restrict__ qkv_b,
    const float* __restrict__ logit_scale, const f16* __restrict__ qkv_wT,
    const f16* __restrict__ bias_f16, const f16* __restrict__ proj_wT,
    const float* __restrict__ proj_b, float* __restrict__ out)
{
    __shared__ alignas(16) f16 xs[64][136];      // 17408 B (x tile, one 128-col half)
    __shared__ alignas(16) f16 slab[8 * 5120];   // 81920 B: per-head qs/kq -> P -> ao
    __shared__ alignas(16) f16 vt[8][32][72];    // 36864 B: v transposed [d][token]
    __shared__ float invk_s[8][64];              // 2048 B

    const int tid = threadIdx.x;
    const int lane = tid & 63;
    const int head = tid >> 6;                   // wave = head
    const int l15 = lane & 15, lq = lane >> 4;
    const int b = blockIdx.x;

    // ---- prefetch per-thread softmax bias rows (consumed much later)
    f16x4 bias_r[16];
    {
        const f16* bh = bias_f16 + head * 4096;
#pragma unroll
        for (int mt = 0; mt < 4; ++mt)
#pragma unroll
            for (int j = 0; j < 4; ++j) {
                int row = mt * 16 + lq * 4 + j;
                bias_r[mt * 4 + j] = *(const f16x4*)(bh + row * 64 + l15 * 4);
            }
    }
    const float lsc = __expf(fminf(logit_scale[head], 4.605170185988091f));

    const float* xb = x + (size_t)b * (49 * 256);
    const int srow = tid >> 5;                   // 0..15
    const int scol = (tid & 31) * 4;             // 0..124

    // ---- stage x half 0
    float4 sreg[4];
#pragma unroll
    for (int i = 0; i < 4; ++i) {
        int r = i * 16 + srow;
        sreg[i] = (r < 49) ? *(const float4*)(xb + r * 256 + scol) : make_float4(0.f, 0.f, 0.f, 0.f);
    }
#pragma unroll
    for (int i = 0; i < 4; ++i) {
        int r = i * 16 + srow;
        f16x4 hv; hv[0] = (f16)sreg[i].x; hv[1] = (f16)sreg[i].y; hv[2] = (f16)sreg[i].z; hv[3] = (f16)sreg[i].w;
        *(f16x4*)(&xs[r][scol]) = hv;
    }
    __syncthreads();

    // ---- issue half-1 loads (overlap with half-0 MFMA)
#pragma unroll
    for (int i = 0; i < 4; ++i) {
        int r = i * 16 + srow;
        sreg[i] = (r < 49) ? *(const float4*)(xb + r * 256 + 128 + scol) : make_float4(0.f, 0.f, 0.f, 0.f);
    }

    f32x4 acc[3][2][4];
#pragma unroll
    for (int ci = 0; ci < 3; ++ci)
#pragma unroll
        for (int nt = 0; nt < 2; ++nt)
#pragma unroll
            for (int mt = 0; mt < 4; ++mt) { acc[ci][nt][mt][0]=0.f; acc[ci][nt][mt][1]=0.f; acc[ci][nt][mt][2]=0.f; acc[ci][nt][mt][3]=0.f; }

    // ---- QKV half 0
#pragma unroll
    for (int ks = 0; ks < 4; ++ks) {
        f16x8 af[4];
#pragma unroll
        for (int mt = 0; mt < 4; ++mt) af[mt] = *(const f16x8*)(&xs[mt * 16 + l15][ks * 32 + lq * 8]);
#pragma unroll
        for (int ci = 0; ci < 3; ++ci)
#pragma unroll
            for (int nt = 0; nt < 2; ++nt) {
                f16x8 bf = *(const f16x8*)(qkv_wT + (size_t)(ci * 256 + head * 32 + nt * 16 + l15) * 256 + ks * 32 + lq * 8);
#pragma unroll
                for (int mt = 0; mt < 4; ++mt)
                    acc[ci][nt][mt] = __builtin_amdgcn_mfma_f32_16x16x32_f16(af[mt], bf, acc[ci][nt][mt], 0, 0, 0);
            }
    }
    __syncthreads();

    // ---- write half 1
#pragma unroll
    for (int i = 0; i < 4; ++i) {
        int r = i * 16 + srow;
        f16x4 hv; hv[0] = (f16)sreg[i].x; hv[1] = (f16)sreg[i].y; hv[2] = (f16)sreg[i].z; hv[3] = (f16)sreg[i].w;
        *(f16x4*)(&xs[r][scol]) = hv;
    }
    __syncthreads();

    // ---- QKV half 1
#pragma unroll
    for (int ks = 0; ks < 4; ++ks) {
        f16x8 af[4];
#pragma unroll
        for (int mt = 0; mt < 4; ++mt) af[mt] = *(const f16x8*)(&xs[mt * 16 + l15][ks * 32 + lq * 8]);
#pragma unroll
        for (int ci = 0; ci < 3; ++ci)
#pragma unroll
            for (int nt = 0; nt < 2; ++nt) {
                f16x8 bf = *(const f16x8*)(qkv_wT + (size_t)(ci * 256 + head * 32 + nt * 16 + l15) * 256 + 128 + ks * 32 + lq * 8);
#pragma unroll
                for (int mt = 0; mt < 4; ++mt)
                    acc[ci][nt][mt] = __builtin_amdgcn_mfma_f32_16x16x32_f16(af[mt], bf, acc[ci][nt][mt], 0, 0, 0);
            }
    }

    // ---- epilogue: v -> vt, q/k -> slab, in-register norms (no barrier: per-head private)
    f16* myslab = slab + head * 5120;
    float bq[2], bk[2], bv2[2];
#pragma unroll
    for (int nt = 0; nt < 2; ++nt) {
        int c = head * 32 + nt * 16 + l15;
        bq[nt] = qkv_b[c]; bk[nt] = qkv_b[256 + c]; bv2[nt] = qkv_b[512 + c];
    }
#pragma unroll
    for (int nt = 0; nt < 2; ++nt)
#pragma unroll
        for (int mt = 0; mt < 4; ++mt)
#pragma unroll
            for (int j = 0; j < 4; ++j) {
                int row = mt * 16 + lq * 4 + j, d = nt * 16 + l15;
                vt[head][d][row] = (f16)(acc[2][nt][mt][j] + bv2[nt]);
            }
    float ssq[4][4], ssk[4][4], invq[4][4], invsum[4][4];
#pragma unroll
    for (int mt = 0; mt < 4; ++mt)
#pragma unroll
        for (int j = 0; j < 4; ++j) {
            float sq = 0.f, sk = 0.f;
            int row = mt * 16 + lq * 4 + j;
#pragma unroll
            for (int nt = 0; nt < 2; ++nt) {
                int d = nt * 16 + l15;
                float qv = acc[0][nt][mt][j] + bq[nt];
                float kv = acc[1][nt][mt][j] + bk[nt];
                myslab[row * 40 + d] = (f16)qv;
                myslab[2560 + row * 40 + d] = (f16)kv;
                sq += qv * qv; sk += kv * kv;
            }
            ssq[mt][j] = sq; ssk[mt][j] = sk;
        }
#pragma unroll
    for (int off = 1; off < 16; off <<= 1)
#pragma unroll
        for (int mt = 0; mt < 4; ++mt)
#pragma unroll
            for (int j = 0; j < 4; ++j) {
                ssq[mt][j] += __shfl_xor(ssq[mt][j], off, 16);
                ssk[mt][j] += __shfl_xor(ssk[mt][j], off, 16);
            }
#pragma unroll
    for (int mt = 0; mt < 4; ++mt)
#pragma unroll
        for (int j = 0; j < 4; ++j) {
            invq[mt][j] = rsqrtf(fmaxf(ssq[mt][j], 1e-20f)) * lsc;
            float ik = rsqrtf(fmaxf(ssk[mt][j], 1e-20f));
            if (l15 == 0) invk_s[head][mt * 16 + lq * 4 + j] = ik;
        }

    // ---- QK^T (K=32, single MFMA step; all per-head private, no barrier)
    f32x4 sacc[4][4];
#pragma unroll
    for (int a = 0; a < 4; ++a)
#pragma unroll
        for (int c = 0; c < 4; ++c) { sacc[a][c][0]=0.f; sacc[a][c][1]=0.f; sacc[a][c][2]=0.f; sacc[a][c][3]=0.f; }
    {
        f16x8 qf[4], kf[4];
#pragma unroll
        for (int mt = 0; mt < 4; ++mt) qf[mt] = *(const f16x8*)(myslab + (mt * 16 + l15) * 40 + lq * 8);
#pragma unroll
        for (int nt = 0; nt < 4; ++nt) kf[nt] = *(const f16x8*)(myslab + 2560 + (nt * 16 + l15) * 40 + lq * 8);
#pragma unroll
        for (int mt = 0; mt < 4; ++mt)
#pragma unroll
            for (int nt = 0; nt < 4; ++nt)
                sacc[mt][nt] = __builtin_amdgcn_mfma_f32_16x16x32_f16(qf[mt], kf[nt], sacc[mt][nt], 0, 0, 0);
    }

    // ---- softmax: unnormalized P -> slab (overlays dead qs/kq); defer 1/sum to output
    float ivk[4];
#pragma unroll
    for (int nt = 0; nt < 4; ++nt) ivk[nt] = invk_s[head][nt * 16 + l15];
#pragma unroll
    for (int mt = 0; mt < 4; ++mt)
#pragma unroll
        for (int j = 0; j < 4; ++j) {
            float iq = invq[mt][j];
            f16x4 br = bias_r[mt * 4 + j];
            float tv[4];
#pragma unroll
            for (int nt = 0; nt < 4; ++nt) {
                int col = nt * 16 + l15;
                float sv = sacc[mt][nt][j] * iq * ivk[nt] + (float)br[nt];
                tv[nt] = (col < 49) ? sv : -1e30f;
            }
            float mx = fmaxf(fmaxf(tv[0], tv[1]), fmaxf(tv[2], tv[3]));
#pragma unroll
            for (int off = 1; off < 16; off <<= 1) mx = fmaxf(mx, __shfl_xor(mx, off, 16));
            float p[4], s = 0.f;
#pragma unroll
            for (int nt = 0; nt < 4; ++nt) { p[nt] = __expf(tv[nt] - mx); s += p[nt]; }
            int row = mt * 16 + lq * 4 + j;
#pragma unroll
            for (int nt = 0; nt < 4; ++nt) myslab[row * 72 + nt * 16 + l15] = (f16)p[nt];
#pragma unroll
            for (int off = 1; off < 16; off <<= 1) s += __shfl_xor(s, off, 16);
            invsum[mt][j] = 1.0f / s;
        }

    // ---- PV (per-head private)
    f32x4 oacc[4][2];
#pragma unroll
    for (int a = 0; a < 4; ++a)
#pragma unroll
        for (int c = 0; c < 2; ++c) { oacc[a][c][0]=0.f; oacc[a][c][1]=0.f; oacc[a][c][2]=0.f; oacc[a][c][3]=0.f; }
#pragma unroll
    for (int kb = 0; kb < 2; ++kb) {
        f16x8 pf[4];
#pragma unroll
        for (int mt = 0; mt < 4; ++mt) pf[mt] = *(const f16x8*)(myslab + (mt * 16 + l15) * 72 + kb * 32 + lq * 8);
#pragma unroll
        for (int nt = 0; nt < 2; ++nt) {
            f16x8 vf = *(const f16x8*)(&vt[head][nt * 16 + l15][kb * 32 + lq * 8]);
#pragma unroll
            for (int mt = 0; mt < 4; ++mt)
                oacc[mt][nt] = __builtin_amdgcn_mfma_f32_16x16x32_f16(pf[mt], vf, oacc[mt][nt], 0, 0, 0);
        }
    }

    // ---- attn tile -> LDS (normalized), then fused proj
    __syncthreads();
    f16 (*ao)[264] = reinterpret_cast<f16(*)[264]>(slab);
#pragma unroll
    for (int mt = 0; mt < 4; ++mt)
#pragma unroll
        for (int j = 0; j < 4; ++j) {
            int row = mt * 16 + lq * 4 + j;
#pragma unroll
            for (int nt = 0; nt < 2; ++nt)
                ao[row][head * 32 + nt * 16 + l15] = (f16)(oacc[mt][nt][j] * invsum[mt][j]);
        }
    __syncthreads();

    f32x4 pacc[4][2];
#pragma unroll
    for (int a = 0; a < 4; ++a)
#pragma unroll
        for (int c = 0; c < 2; ++c) { pacc[a][c][0]=0.f; pacc[a][c][1]=0.f; pacc[a][c][2]=0.f; pacc[a][c][3]=0.f; }
#pragma unroll
    for (int ks = 0; ks < 8; ++ks) {
        f16x8 af2[4];
#pragma unroll
        for (int mt = 0; mt < 4; ++mt) af2[mt] = *(const f16x8*)(&ao[mt * 16 + l15][ks * 32 + lq * 8]);
#pragma unroll
        for (int nt = 0; nt < 2; ++nt) {
            f16x8 bf = *(const f16x8*)(proj_wT + (size_t)(head * 32 + nt * 16 + l15) * 256 + ks * 32 + lq * 8);
#pragma unroll
            for (int mt = 0; mt < 4; ++mt)
                pacc[mt][nt] = __builtin_amdgcn_mfma_f32_16x16x32_f16(af2[mt], bf, pacc[mt][nt], 0, 0, 0);
        }
    }
    float pb[2];
#pragma unroll
    for (int nt = 0; nt < 2; ++nt) pb[nt] = proj_b[head * 32 + nt * 16 + l15];
#pragma unroll
    for (int mt = 0; mt < 4; ++mt)
#pragma unroll
        for (int j = 0; j < 4; ++j) {
            int row = mt * 16 + lq * 4 + j;
            if (row < 49) {
                float* orow = out + ((size_t)(b * 49 + row)) * 256 + head * 32;
#pragma unroll
                for (int nt = 0; nt < 2; ++nt)
                    orow[nt * 16 + l15] = pacc[mt][nt][j] + pb[nt];
            }
        }
}

extern "C" void kernel_launch(void* const* d_in, const int* in_sizes, int n_in,
                              void* d_out, int out_size, void* d_ws, size_t ws_size,
                              hipStream_t stream) {
    const float* x           = (const float*)d_in[0];
    const float* qkv_w       = (const float*)d_in[1];
    const float* qkv_b       = (const float*)d_in[2];
    const float* proj_w      = (const float*)d_in[3];
    const float* proj_b      = (const float*)d_in[4];
    const float* logit_scale = (const float*)d_in[5];
    const float* cpb_w1      = (const float*)d_in[6];
    const float* cpb_b1      = (const float*)d_in[7];
    const float* cpb_w2      = (const float*)d_in[8];
    float* out = (float*)d_out;

    const int B = in_sizes[0] / (49 * 256);
    char* ws = (char*)d_ws;
    f16* bias_f16 = (f16*)(ws + WS_BIAS);
    float* tbl_ws = (float*)(ws + WS_TBL);
    f16* qkv_wT   = (f16*)(ws + WS_QKVWT);
    f16* proj_wT  = (f16*)(ws + WS_PROJWT);

    hipLaunchKernelGGL(cpb_mlp_kernel, dim3(169), dim3(512), 0, stream, cpb_w1, cpb_b1, cpb_w2, tbl_ws);
    hipLaunchKernelGGL(cpb_bias_kernel, dim3(128), dim3(256), 0, stream, tbl_ws, bias_f16);
    hipLaunchKernelGGL(wconv_kernel, dim3(64), dim3(256), 0, stream, qkv_w, proj_w, qkv_wT, proj_wT);
    hipLaunchKernelGGL(fused_kernel, dim3(B), dim3(512), 0, stream,
                       x, qkv_b, logit_scale, qkv_wT, bias_f16, proj_wT, proj_b, out);
}